// Round 13
// baseline (2012.281 us; speedup 1.0000x reference)
//
#include <hip/hip_runtime.h>
#include <stdint.h>

// ---------------- problem constants ----------------
#define S_LEN   8192
#define DMODEL  3072
#define HDIM    768
#define NLM     32
#define MTOK    16384          // B*S token rows
#define MV      16448          // + 2*32 landmark rows
#define MP      16512          // padded (A/CTX allocation rows)
#define NQKV    9216
#define KDIM    3072
#define NKT32   96             // K-tiles of 32 (BK=32)
#define MTILES  64             // M-tiles of 256 (TOKEN rows only)
#define SCALE_F 0.036084391824351615f   // 1/sqrt(768)

// ---------------- workspace layout (bytes) ----------------
#define OFF_A    ((size_t)0)
#define OFF_WT   ((size_t)101449728)
#define OFF_QKV  ((size_t)176947200)
#define OFF_CTX  ((size_t)480116736)
#define OFF_BCAT ((size_t)581566464)
#define OFF_PART ((size_t)581615616)
#define OFF_KT   (OFF_PART)
#define OFF_VT   (OFF_PART + 393216)
#define OFF_ML2  (OFF_PART + 786432)
#define OFF_LMP  (OFF_PART + 917504)   // 6 x 64 x 9216 f32 = 14.2 MB
#define OFF_CP   (OFF_A)               // lm ctx partials: 16384 x 768 f32

#if defined(__has_builtin)
#if __has_builtin(__builtin_amdgcn_global_load_lds)
#define USE_GLL 1
#endif
#endif
#ifndef USE_GLL
#define USE_GLL 0
#endif

typedef __attribute__((ext_vector_type(8))) short bf8_t;             // 8 bf16 (4 VGPR) MFMA frag
typedef __attribute__((ext_vector_type(4))) float f4_t;
typedef __attribute__((ext_vector_type(4))) short s4_t;
typedef __attribute__((ext_vector_type(4))) unsigned short us4_t;

__device__ __forceinline__ float b2f(unsigned short u) {
  unsigned x = ((unsigned)u) << 16;
  float f;
  __builtin_memcpy(&f, &x, 4);
  return f;
}
__device__ __forceinline__ unsigned short f2b(float f) {  // RNE bf16
  unsigned x;
  __builtin_memcpy(&x, &f, 4);
  x += 0x7fffu + ((x >> 16) & 1u);
  return (unsigned short)(x >> 16);
}
__device__ __forceinline__ void load12(const unsigned short* p, float* f) {
  s4_t v0 = *(const s4_t*)p;
  s4_t v1 = *(const s4_t*)(p + 4);
  s4_t v2 = *(const s4_t*)(p + 8);
#pragma unroll
  for (int e = 0; e < 4; ++e) {
    f[e]     = b2f((unsigned short)v0[e]);
    f[4 + e] = b2f((unsigned short)v1[e]);
    f[8 + e] = b2f((unsigned short)v2[e]);
  }
}
__device__ __forceinline__ void store12(unsigned short* p, const float* f) {
  us4_t a = {f2b(f[0]), f2b(f[1]), f2b(f[2]), f2b(f[3])};
  us4_t b = {f2b(f[4]), f2b(f[5]), f2b(f[6]), f2b(f[7])};
  us4_t c = {f2b(f[8]), f2b(f[9]), f2b(f[10]), f2b(f[11])};
  *(us4_t*)p = a;
  *(us4_t*)(p + 4) = b;
  *(us4_t*)(p + 8) = c;
}

// ---------------- K0: fused prep — bcat | A-matrix | weight transpose x4 ------
__global__ __launch_bounds__(256) void prep(const float* __restrict__ hs,
                                            const float* __restrict__ lemb,
                                            const float* __restrict__ bq,
                                            const float* __restrict__ bk,
                                            const float* __restrict__ bv,
                                            const float* __restrict__ bo,
                                            const float* __restrict__ W0,
                                            const float* __restrict__ W1,
                                            const float* __restrict__ W2,
                                            const float* __restrict__ W3,
                                            unsigned short* __restrict__ A,
                                            unsigned short* __restrict__ Wt,
                                            float* __restrict__ bcat) {
  __shared__ float t[32][33];
  int blk = blockIdx.x;
  int tid = threadIdx.x;
  if (blk < 48) {                                    // ---- bcat
    int n = blk * 256 + tid;                         // 0..12287
    float v = (n < 3072) ? bq[n] : (n < 6144) ? bk[n - 3072]
            : (n < 9216) ? bv[n - 6144] : bo[n - 9216];
    bcat[n] = v;
    return;
  }
  if (blk < 48 + 49536) {                            // ---- build_a
    size_t idx = (size_t)(blk - 48) * 256 + tid;
    size_t e = idx * 4;
    int row = (int)(e / DMODEL);
    int col = (int)(e - (size_t)row * DMODEL);
    f4_t v;
    if (row < MTOK) {
      v = *(const f4_t*)(hs + e);
    } else if (row < MV) {
      int r2 = row - MTOK;
      int b = r2 >> 5, j = r2 & 31;
      int sel = (j * 511) / 31;        // matches linspace(0,511,32) truncation
      int li = sel * 16;
      f4_t a = *(const f4_t*)(hs + ((size_t)(b * S_LEN + li)) * DMODEL + col);
      f4_t c = *(const f4_t*)(lemb + (size_t)j * DMODEL + col);
      v = a + c;
    } else {
      v = (f4_t){0.f, 0.f, 0.f, 0.f};
    }
    us4_t o = {f2b(v[0]), f2b(v[1]), f2b(v[2]), f2b(v[3])};
    *(us4_t*)(A + e) = o;
    return;
  }
  // ---- wtrans x4 (flattened 96x96x4)
  int i2 = blk - 49584;
  int z = i2 / 9216;
  int rem = i2 - z * 9216;
  int by = rem / 96, bx = rem - by * 96;
  const float* Wsel[4] = {W0, W1, W2, W3};
  const float* W = Wsel[z];
  unsigned short* dst = Wt + (size_t)z * 3072 * KDIM;
  int n0 = bx * 32, k0 = by * 32;
  int x = tid & 31, y = tid >> 5;                    // (32,8)
#pragma unroll
  for (int i = 0; i < 4; ++i)
    t[y + i * 8][x] = W[(size_t)(k0 + y + i * 8) * DMODEL + n0 + x];
  __syncthreads();
#pragma unroll
  for (int i = 0; i < 4; ++i)
    dst[(size_t)(n0 + y + i * 8) * DMODEL + k0 + x] = f2b(t[x][y + i * 8]);
}

// ---------------- K1b: split-K landmark GEMM partials ----------------
__global__ __launch_bounds__(256) void lm_gemm_part(const unsigned short* __restrict__ A64,
                                                    const unsigned short* __restrict__ Bt,
                                                    float* __restrict__ part,
                                                    int N) {
  int wid = blockIdx.x * 4 + (threadIdx.x >> 6);
  int lane = threadIdx.x & 63;
  int row16 = lane & 15, quad = lane >> 4;
  int strips = N >> 5;
  int ks = wid / strips;
  int n0 = (wid - ks * strips) * 32;

  f4_t acc[4][2];
#pragma unroll
  for (int mi = 0; mi < 4; ++mi) {
    acc[mi][0] = (f4_t){0.f, 0.f, 0.f, 0.f};
    acc[mi][1] = (f4_t){0.f, 0.f, 0.f, 0.f};
  }
#pragma unroll 4
  for (int kt = ks * 16; kt < ks * 16 + 16; ++kt) {
    int k = kt * 32 + quad * 8;
    bf8_t b0 = *(const bf8_t*)(Bt + (size_t)(n0 + row16) * KDIM + k);
    bf8_t b1 = *(const bf8_t*)(Bt + (size_t)(n0 + 16 + row16) * KDIM + k);
#pragma unroll
    for (int mi = 0; mi < 4; ++mi) {
      bf8_t a = *(const bf8_t*)(A64 + (size_t)(mi * 16 + row16) * KDIM + k);
      acc[mi][0] = __builtin_amdgcn_mfma_f32_16x16x32_bf16(a, b0, acc[mi][0], 0, 0, 0);
      acc[mi][1] = __builtin_amdgcn_mfma_f32_16x16x32_bf16(a, b1, acc[mi][1], 0, 0, 0);
    }
  }
#pragma unroll
  for (int mi = 0; mi < 4; ++mi)
#pragma unroll
    for (int i = 0; i < 4; ++i) {
      int r = mi * 16 + quad * 4 + i;
#pragma unroll
      for (int nl = 0; nl < 2; ++nl) {
        int col = n0 + nl * 16 + row16;
        part[((size_t)ks * 64 + r) * N + col] = acc[mi][nl][i];
      }
    }
}

// ---------------- K1c: combine split-K partials + bias -> bf16 (+ optional KT/VT) ----
__global__ __launch_bounds__(256) void lm_gemm_fix(const float* __restrict__ part,
                                                   const float* __restrict__ bias,
                                                   unsigned short* __restrict__ C64,
                                                   int N,
                                                   unsigned short* __restrict__ KT,
                                                   unsigned short* __restrict__ VT) {
  int idx = blockIdx.x * 256 + threadIdx.x;          // one f32x4 per thread
  int nq = N >> 2;
  int r = idx / nq;
  int c4 = (idx - r * nq) * 4;
  if (r >= 64) return;
  f4_t s = *(const f4_t*)(part + (size_t)r * N + c4);
#pragma unroll
  for (int ks = 1; ks < 6; ++ks)
    s += *(const f4_t*)(part + ((size_t)ks * 64 + r) * N + c4);
  f4_t bb = *(const f4_t*)(bias + c4);
  s += bb;
  us4_t o = {f2b(s[0]), f2b(s[1]), f2b(s[2]), f2b(s[3])};
  *(us4_t*)(C64 + (size_t)r * N + c4) = o;

  if (KT) {
    int b = r >> 5, j = r & 31;
    if (c4 >= 3072 && c4 < 6144) {                   // K third -> KT
      int cc = c4 - 3072;
      int h = cc / 768, c0 = cc - h * 768;           // c0 4-aligned
      int bh = b * 4 + h;
      *(us4_t*)(KT + (size_t)bh * 24576 + ((size_t)(c0 >> 3) * 32 + j) * 8 + (c0 & 7)) = o;
    } else if (c4 >= 6144) {                         // V third -> VT
      int cc = c4 - 6144;
      int h = cc / 768, d0 = cc - h * 768;
      int bh = b * 4 + h;
      unsigned short* vt = VT + (size_t)bh * 24576 + (size_t)d0 * 32 + j;
#pragma unroll
      for (int k = 0; k < 4; ++k) vt[(size_t)k * 32] = (unsigned short)o[k];
    }
  }
}

// ---------------- K2: 256x256 bf16 MFMA GEMM, BK=32, 64KB LDS ----------------
// R13: retry of R11's occupancy experiment with the launch_bounds bug fixed.
// R11 used (512,4) -> hard 128-VGPR cap -> allocator dropped to 64-VGPR tier
// and spilled acc (26GB scratch).  Here (512,2) leaves the allocator free;
// the BK=32 body's live set <= BK=64's (which allocates 124), and at <=128
// VGPR the HW naturally schedules 4 waves/SIMD = 2 blocks/CU with 64KB LDS.
// Numerics: MFMA order bitwise identical to BK=64 (ascending k).  Swizzle/
// lifetime logic verified correct by R11's passing refcheck.
#if USE_GLL
#define GLL16(SRC, OFF)                                                        \
  __builtin_amdgcn_global_load_lds(                                           \
      (const __attribute__((address_space(1))) void*)(SRC),                   \
      (__attribute__((address_space(3))) void*)(lds + (OFF)), 16, 0, 0)
#else
#define GLL16(SRC, OFF)                                                        \
  (*(bf8_t*)(lds + (OFF) + (unsigned)(threadIdx.x & 63) * 16) = *(const bf8_t*)(SRC))
#endif

#define STG32_A(TT, DD)                                                        \
  do {                                                                         \
    const unsigned short* _s = gA0 + (size_t)(TT) * 32;                        \
    GLL16(_s, (unsigned)((DD) * 16384) + wl16);                                \
    GLL16(_s + (size_t)128 * KDIM, (unsigned)((DD) * 16384 + 8192) + wl16);    \
  } while (0)
#define STG32_B(TT, DD)                                                        \
  do {                                                                         \
    const unsigned short* _s = gB0 + (size_t)(TT) * 32;                        \
    GLL16(_s, (unsigned)(32768 + (DD) * 16384) + wl16);                        \
    GLL16(_s + (size_t)128 * KDIM,                                             \
          (unsigned)(32768 + (DD) * 16384 + 8192) + wl16);                     \
  } while (0)

#define LDA32(DD, QM, MI)                                                      \
  (*(const bf8_t*)(lds + (DD) * 16384 + aBase + (QM) * 4096 + (MI) * 1024))
#define LDB32(DD, NI)                                                          \
  (*(const bf8_t*)(lds + (DD) * 16384 + bBase + (NI) * 1024))

#define MFMA16(Q, A0, A1, A2, A3, B0, B1, B2, B3)                              \
  do {                                                                         \
    __builtin_amdgcn_s_setprio(1);                                             \
    acc[(Q)+0][0] = __builtin_amdgcn_mfma_f32_16x16x32_bf16(A0, B0, acc[(Q)+0][0], 0, 0, 0); \
    acc[(Q)+1][0] = __builtin_amdgcn_mfma_f32_16x16x32_bf16(A1, B0, acc[(Q)+1][0], 0, 0, 0); \
    acc[(Q)+2][0] = __builtin_amdgcn_mfma_f32_16x16x32_bf16(A2, B0, acc[(Q)+2][0], 0, 0, 0); \
    acc[(Q)+3][0] = __builtin_amdgcn_mfma_f32_16x16x32_bf16(A3, B0, acc[(Q)+3][0], 0, 0, 0); \
    acc[(Q)+0][1] = __builtin_amdgcn_mfma_f32_16x16x32_bf16(A0, B1, acc[(Q)+0][1], 0, 0, 0); \
    acc[(Q)+1][1] = __builtin_amdgcn_mfma_f32_16x16x32_bf16(A1, B1, acc[(Q)+1][1], 0, 0, 0); \
    acc[(Q)+2][1] = __builtin_amdgcn_mfma_f32_16x16x32_bf16(A2, B1, acc[(Q)+2][1], 0, 0, 0); \
    acc[(Q)+3][1] = __builtin_amdgcn_mfma_f32_16x16x32_bf16(A3, B1, acc[(Q)+3][1], 0, 0, 0); \
    acc[(Q)+0][2] = __builtin_amdgcn_mfma_f32_16x16x32_bf16(A0, B2, acc[(Q)+0][2], 0, 0, 0); \
    acc[(Q)+1][2] = __builtin_amdgcn_mfma_f32_16x16x32_bf16(A1, B2, acc[(Q)+1][2], 0, 0, 0); \
    acc[(Q)+2][2] = __builtin_amdgcn_mfma_f32_16x16x32_bf16(A2, B2, acc[(Q)+2][2], 0, 0, 0); \
    acc[(Q)+3][2] = __builtin_amdgcn_mfma_f32_16x16x32_bf16(A3, B2, acc[(Q)+3][2], 0, 0, 0); \
    acc[(Q)+0][3] = __builtin_amdgcn_mfma_f32_16x16x32_bf16(A0, B3, acc[(Q)+0][3], 0, 0, 0); \
    acc[(Q)+1][3] = __builtin_amdgcn_mfma_f32_16x16x32_bf16(A1, B3, acc[(Q)+1][3], 0, 0, 0); \
    acc[(Q)+2][3] = __builtin_amdgcn_mfma_f32_16x16x32_bf16(A2, B3, acc[(Q)+2][3], 0, 0, 0); \
    acc[(Q)+3][3] = __builtin_amdgcn_mfma_f32_16x16x32_bf16(A3, B3, acc[(Q)+3][3], 0, 0, 0); \
    __builtin_amdgcn_s_setprio(0);                                             \
  } while (0)

__global__ __launch_bounds__(512, 2) void gemm256(const unsigned short* __restrict__ A,
                                                  const unsigned short* __restrict__ Bt,
                                                  const float* __restrict__ bias,
                                                  unsigned short* __restrict__ C,
                                                  int N, int Ntiles) {
  extern __shared__ char lds[];
  const int tid = threadIdx.x;
  const int lane = tid & 63;
  const int wave = tid >> 6;
  const int WM = wave >> 2;                          // 0..1 (128-row half)
  const int WN = wave & 3;                           // 0..3 (64-col strip)
  const int row16 = lane & 15, quad = lane >> 4;

  // T1: bijective XCD-aware remap (m204)
  int nwg = (int)gridDim.x;
  int orig = (int)blockIdx.x;
  int q = nwg >> 3, r = nwg & 7;
  int xcd = orig & 7, lin = orig >> 3;
  int wg = (xcd < r ? xcd * (q + 1) : r * (q + 1) + (xcd - r) * q) + lin;

  // N-group-major tile order, N_RECT=8: (g, m, nl) with nl fastest.
  int g = wg / (MTILES * 8);
  int w2 = wg - g * (MTILES * 8);
  int Ng = Ntiles - g * 8;
  int m_, nl;
  if (Ng >= 8) { m_ = w2 >> 3; nl = w2 & 7; }
  else         { m_ = w2 / Ng; nl = w2 - m_ * Ng; }
  const int tileM = m_ * 256;
  const int tileN = (g * 8 + nl) * 256;

  // staging: thread -> (row = tid>>2 [+128], slot = tid&3); source chunk
  // pre-swizzled (c = slot ^ ((row>>1)&3)) so linear gll dest = swizzled LDS.
  const int srow = tid >> 2;                         // 0..127
  const int scq = (tid & 3) ^ ((srow >> 1) & 3);
  const unsigned short* gA0 = A + (size_t)(tileM + srow) * KDIM + scq * 8;
  const unsigned short* gB0 = Bt + (size_t)(tileN + srow) * KDIM + scq * 8;
  const unsigned wl16 = (unsigned)(tid & 448) * 16;  // wave-uniform LDS base part

  const unsigned co = (unsigned)((quad * 16) ^ (((row16 >> 1) & 3) << 4));
  const unsigned aBase = (unsigned)(WM * 8192 + row16 * 64) + co;
  const unsigned bBase = 32768u + (unsigned)(WN * 4096 + row16 * 64) + co;

  f4_t acc[8][4];
#pragma unroll
  for (int a = 0; a < 8; ++a)
#pragma unroll
    for (int b = 0; b < 4; ++b) acc[a][b] = (f4_t){0.f, 0.f, 0.f, 0.f};

  STG32_A(0, 0); STG32_B(0, 0);
  asm volatile("s_waitcnt vmcnt(0)" ::: "memory");
  __builtin_amdgcn_s_barrier();

#pragma unroll 2
  for (int t = 0; t < NKT32; ++t) {
    const int d = t & 1;
    {  // P0: qm=0 (+ stage next tile into buf d^1)
      bf8_t a0 = LDA32(d, 0, 0), a1 = LDA32(d, 0, 1),
            a2 = LDA32(d, 0, 2), a3 = LDA32(d, 0, 3);
      bf8_t b0 = LDB32(d, 0), b1 = LDB32(d, 1),
            b2 = LDB32(d, 2), b3 = LDB32(d, 3);
      if (t + 1 < NKT32) { STG32_A(t + 1, d ^ 1); STG32_B(t + 1, d ^ 1); }
      __builtin_amdgcn_s_barrier();
      asm volatile("s_waitcnt lgkmcnt(0)");
      MFMA16(0, a0, a1, a2, a3, b0, b1, b2, b3);
      __builtin_amdgcn_s_barrier();
      // P1: qm=1 (B frags reused from registers)
      bf8_t a4 = LDA32(d, 1, 0), a5 = LDA32(d, 1, 1),
            a6 = LDA32(d, 1, 2), a7 = LDA32(d, 1, 3);
      __builtin_amdgcn_s_barrier();
      asm volatile("s_waitcnt lgkmcnt(0)");
      MFMA16(4, a4, a5, a6, a7, b0, b1, b2, b3);
      asm volatile("s_waitcnt vmcnt(0)" ::: "memory");
      __builtin_amdgcn_s_barrier();
    }
  }

  float bv_[4];
#pragma unroll
  for (int ni = 0; ni < 4; ++ni) bv_[ni] = bias[tileN + WN * 64 + ni * 16 + row16];
#pragma unroll
  for (int mi = 0; mi < 8; ++mi) {
#pragma unroll
    for (int i = 0; i < 4; ++i) {
      int grow = tileM + WM * 128 + mi * 16 + quad * 4 + i;
      size_t base = (size_t)grow * N + tileN + WN * 64 + row16;
#pragma unroll
      for (int ni = 0; ni < 4; ++ni)
        C[base + ni * 16] = f2b(acc[mi][ni][i] + bv_[ni]);
    }
  }
}

// ---------------- K3: fused attention — glob_attn + lm_attn_part ----------------
__global__ __launch_bounds__(256, 2) void attn_fused(const unsigned short* __restrict__ QKV,
                                                     const unsigned short* __restrict__ KT,
                                                     const unsigned short* __restrict__ VT,
                                                     unsigned short* __restrict__ CTX,
                                                     float* __restrict__ ctxpart,
                                                     float* __restrict__ mlpart) {
  __shared__ unsigned short P_s[4][32][32];          // [wave][row][landmark]
  const int tid = threadIdx.x;
  const int lane = tid & 63;
  const int row16 = lane & 15, quad = lane >> 4;

  if (blockIdx.x < 512) {
    // ================= glob_attn =================
    const int w = tid >> 6;
    const int qt = blockIdx.x & 63;
    const int h = (blockIdx.x >> 6) & 3;
    const int b = blockIdx.x >> 8;
    const int bh = b * 4 + h;
    const int rowbase = b * S_LEN + qt * 128 + w * 32;

    const unsigned short* KTb = KT + (size_t)bh * 24576;
    const unsigned short* VTb = VT + (size_t)bh * 24576;

    f4_t sc[2][2];
#pragma unroll
    for (int mi = 0; mi < 2; ++mi)
#pragma unroll
      for (int ni = 0; ni < 2; ++ni) sc[mi][ni] = (f4_t){0.f, 0.f, 0.f, 0.f};

#pragma unroll
    for (int kt = 0; kt < 24; ++kt) {
      bf8_t kb0 = *(const bf8_t*)(KTb + (size_t)((kt * 4 + quad) * 32 + row16) * 8);
      bf8_t kb1 = *(const bf8_t*)(KTb + (size_t)((kt * 4 + quad) * 32 + 16 + row16) * 8);
      bf8_t qa0 = *(const bf8_t*)(QKV + (size_t)(rowbase + row16) * NQKV + h * HDIM +
                                  kt * 32 + quad * 8);
      bf8_t qa1 = *(const bf8_t*)(QKV + (size_t)(rowbase + 16 + row16) * NQKV + h * HDIM +
                                  kt * 32 + quad * 8);
      sc[0][0] = __builtin_amdgcn_mfma_f32_16x16x32_bf16(qa0, kb0, sc[0][0], 0, 0, 0);
      sc[0][1] = __builtin_amdgcn_mfma_f32_16x16x32_bf16(qa0, kb1, sc[0][1], 0, 0, 0);
      sc[1][0] = __builtin_amdgcn_mfma_f32_16x16x32_bf16(qa1, kb0, sc[1][0], 0, 0, 0);
      sc[1][1] = __builtin_amdgcn_mfma_f32_16x16x32_bf16(qa1, kb1, sc[1][1], 0, 0, 0);
    }

#pragma unroll
    for (int mi = 0; mi < 2; ++mi) {
#pragma unroll
      for (int i = 0; i < 4; ++i) {
        float s0 = sc[mi][0][i] * SCALE_F;
        float s1 = sc[mi][1][i] * SCALE_F;
        float mx = fmaxf(s0, s1);
#pragma unroll
        for (int off = 8; off; off >>= 1) mx = fmaxf(mx, __shfl_xor(mx, off));
        float p0 = __expf(s0 - mx), p1 = __expf(s1 - mx);
        float sum = p0 + p1;
#pragma unroll
        for (int off = 8; off; off >>= 1) sum += __shfl_xor(sum, off);
        float inv = 1.f / sum;
        int rr = mi * 16 + quad * 4 + i;
        P_s[w][rr][row16] = f2b(p0 * inv);
        P_s[w][rr][16 + row16] = f2b(p1 * inv);
      }
    }
    __syncthreads();

    bf8_t pa0 = *(const bf8_t*)&P_s[w][row16][quad * 8];
    bf8_t pa1 = *(const bf8_t*)&P_s[w][16 + row16][quad * 8];
    unsigned short* ctxb = CTX + (size_t)rowbase * DMODEL + h * HDIM;

#pragma unroll
    for (int dch = 0; dch < 12; ++dch) {
      bf8_t vb[4];
#pragma unroll
      for (int ni = 0; ni < 4; ++ni)
        vb[ni] = *(const bf8_t*)(VTb + (size_t)(dch * 64 + ni * 16 + row16) * 32 + quad * 8);
#pragma unroll
      for (int mi = 0; mi < 2; ++mi) {
        bf8_t pa = mi ? pa1 : pa0;
#pragma unroll
        for (int ni = 0; ni < 4; ++ni) {
          f4_t c = __builtin_amdgcn_mfma_f32_16x16x32_bf16(
              pa, vb[ni], (f4_t){0.f, 0.f, 0.f, 0.f}, 0, 0, 0);
#pragma unroll
          for (int i = 0; i < 4; ++i)
            ctxb[(size_t)(mi * 16 + quad * 4 + i) * DMODEL + dch * 64 + ni * 16 + row16] =
                f2b(c[i]);
        }
      }
    }
    return;
  }

  // ================= lm_attn_part (JG=8, 64 k-chunks of 128) =================
  int wid = (blockIdx.x - 512) * 4 + (tid >> 6);     // 0..2047
  int jg = wid & 3, kc = (wid >> 2) & 63, h = (wid >> 8) & 3, b = wid >> 10;

  float qreg[8][12];
#pragma unroll
  for (int jj = 0; jj < 8; ++jj)
    load12(QKV + (size_t)(MTOK + b * NLM + jg * 8 + jj) * NQKV + h * HDIM + lane * 12,
           qreg[jj]);

  float m[8], l[8], ctx[8][12];
#pragma unroll
  for (int jj = 0; jj < 8; ++jj) {
    m[jj] = -1e30f;
    l[jj] = 0.f;
#pragma unroll
    for (int e = 0; e < 12; ++e) ctx[jj][e] = 0.f;
  }

  for (int k = kc * 128; k < kc * 128 + 128; ++k) {
    size_t row = (size_t)(b * S_LEN + k);
    float kv[12], vv[12];
    load12(QKV + row * NQKV + DMODEL + h * HDIM + lane * 12, kv);
    float s[8];
#pragma unroll
    for (int jj = 0; jj < 8; ++jj) {
      float p = 0.f;
#pragma unroll
      for (int e = 0; e < 12; ++e) p += qreg[jj][e] * kv[e];
      s[jj] = p;
    }
#pragma unroll
    for (int jj = 0; jj < 8; ++jj) {
#pragma unroll
      for (int off = 32; off; off >>= 1) s[jj] += __shfl_xor(s[jj], off);
      s[jj] *= SCALE_F;
    }
    load12(QKV + row * NQKV + 2 * DMODEL + h * HDIM + lane * 12, vv);
#pragma unroll
    for (int jj = 0; jj < 8; ++jj) {
      if (s[jj] <= m[jj]) {                          // wave-uniform branch
        float pp = __expf(s[jj] - m[jj]);
        l[jj] += pp;
#pragma unroll
        for (int e = 0; e < 12; ++e) ctx[jj][e] += pp * vv[e];
      } else {
        float al = __expf(m[jj] - s[jj]);
        m[jj] = s[jj];
        l[jj] = l[jj] * al + 1.f;
#pragma unroll
        for (int e = 0; e < 12; ++e) ctx[jj][e] = ctx[jj][e] * al + vv[e];
      }
    }
  }

#pragma unroll
  for (int jj = 0; jj < 8; ++jj) {
    int p = (((b * 4 + h) * 32) + (jg * 8 + jj)) * 64 + kc;
    float* cp = ctxpart + (size_t)p * HDIM + lane * 12;
#pragma unroll
    for (int e = 0; e < 12; ++e) cp[e] = ctx[jj][e];
    if (lane == 0) {
      mlpart[p * 2] = m[jj];
      mlpart[p * 2 + 1] = l[jj];
    }
  }
}

// ---------------- K4b: merge 64 landmark partials, wave per (b,h,j) ----------------
__global__ __launch_bounds__(256) void lm_combine(const float* __restrict__ ctxpart,
                                                  const float* __restrict__ mlpart,
                                                  unsigned short* __restrict__ CTX) {
  int wid = blockIdx.x * 4 + (threadIdx.x >> 6);     // 0..255
  int lane = threadIdx.x & 63;
  int j = wid & 31, h = (wid >> 5) & 3, b = wid >> 7;
  int base = wid * 64;
  float mk = mlpart[(base + lane) * 2];
  float lk = mlpart[(base + lane) * 2 + 1];
  float mm = mk;
#pragma unroll
  for (int off = 32; off; off >>= 1) mm = fmaxf(mm, __shfl_xor(mm, off));
  float al = __expf(mk - mm);
  float ls = al * lk;
#pragma unroll
  for (int off = 32; off; off >>= 1) ls += __shfl_xor(ls, off);

  float ctx[12];
#pragma unroll
  for (int e = 0; e < 12; ++e) ctx[e] = 0.f;
  for (int kc = 0; kc < 64; ++kc) {
    float a = __shfl(al, kc);
    const float* cp = ctxpart + (size_t)(base + kc) * HDIM + lane * 12;
#pragma unroll
    for (int e = 0; e < 12; ++e) ctx[e] += a * cp[e];
  }
  float inv = 1.f / ls;
#pragma unroll
  for (int e = 0; e < 12; ++e) ctx[e] *= inv;
  store12(CTX + (size_t)(MTOK + b * NLM + j) * DMODEL + h * HDIM + lane * 12, ctx);
}

// ---------------- K6: out = (landmark? lm_proj : hs) + global_proj, 8 elems/thread ----
__global__ __launch_bounds__(256) void compose(const float* __restrict__ hs,
                                               const unsigned short* __restrict__ PROJ,
                                               float* __restrict__ out) {
  size_t idx = (size_t)blockIdx.x * 256 + threadIdx.x;
  size_t e = idx * 8;
  int row = (int)(e / DMODEL);
  int col = (int)(e - (size_t)row * DMODEL);
  int b = row >> 13, s = row & (S_LEN - 1);

  us4_t g4a = *(const us4_t*)(PROJ + (size_t)row * DMODEL + col);
  us4_t g4b = *(const us4_t*)(PROJ + (size_t)row * DMODEL + col + 4);
  int j = -1;
  if ((s & 15) == 0) {
    int sel = s >> 4;
    int jc = (sel * 31 + 510) / 511;                 // ceil(sel*31/511): unique candidate
    if (jc < 32 && (jc * 511) / 31 == sel) j = jc;
  }
  f4_t ba, bb;
  if (j >= 0) {
    const unsigned short* lp = PROJ + (size_t)(MTOK + b * NLM + j) * DMODEL + col;
    us4_t l4a = *(const us4_t*)lp;
    us4_t l4b = *(const us4_t*)(lp + 4);
    ba = (f4_t){b2f(l4a[0]), b2f(l4a[1]), b2f(l4a[2]), b2f(l4a[3])};
    bb = (f4_t){b2f(l4b[0]), b2f(l4b[1]), b2f(l4b[2]), b2f(l4b[3])};
  } else {
    ba = *(const f4_t*)(hs + e);
    bb = *(const f4_t*)(hs + e + 4);
  }
  f4_t oa = {ba[0] + b2f(g4a[0]), ba[1] + b2f(g4a[1]),
             ba[2] + b2f(g4a[2]), ba[3] + b2f(g4a[3])};
  f4_t ob = {bb[0] + b2f(g4b[0]), bb[1] + b2f(g4b[1]),
             bb[2] + b2f(g4b[2]), bb[3] + b2f(g4b[3])};
  *(f4_t*)(out + e) = oa;
  *(f4_t*)(out + e + 4) = ob;
}

// ---------------- launch ----------------
extern "C" void kernel_launch(void* const* d_in, const int* in_sizes, int n_in,
                              void* d_out, int out_size, void* d_ws, size_t ws_size,
                              hipStream_t stream) {
  const float* hs   = (const float*)d_in[0];
  const float* lemb = (const float*)d_in[1];
  const float* Wq   = (const float*)d_in[2];
  const float* bq   = (const float*)d_in[3];
  const float* Wk   = (const float*)d_in[4];
  const float* bk   = (const float*)d_in[5];
  const float* Wv   = (const float*)d_in[6];
  const float* bv   = (const float*)d_in[7];
  const float* Wo   = (const float*)d_in[8];
  const float* bo   = (const float*)d_in[9];
  float* out = (float*)d_out;
  char* ws = (char*)d_ws;

  unsigned short* A    = (unsigned short*)(ws + OFF_A);
  unsigned short* Wt   = (unsigned short*)(ws + OFF_WT);
  unsigned short* QKV  = (unsigned short*)(ws + OFF_QKV);
  unsigned short* CTX  = (unsigned short*)(ws + OFF_CTX);
  float*          bcat = (float*)(ws + OFF_BCAT);
  unsigned short* KT   = (unsigned short*)(ws + OFF_KT);
  unsigned short* VT   = (unsigned short*)(ws + OFF_VT);
  float*          ml   = (float*)(ws + OFF_ML2);
  float*          lmp  = (float*)(ws + OFF_LMP);
  float*          cpart= (float*)(ws + OFF_CP);          // A region (dead window)
  unsigned short* PROJ = (unsigned short*)(ws + OFF_A);  // after lm_combine

  static bool attr_set = false;
  if (!attr_set) {
    (void)hipFuncSetAttribute(reinterpret_cast<const void*>(gemm256),
                              hipFuncAttributeMaxDynamicSharedMemorySize, 65536);
    attr_set = true;
  }

  // fused prep: bcat(48) + build_a(49536) + wtrans(36864)
  prep<<<dim3(48 + 49536 + 36864), dim3(256), 0, stream>>>(
      hs, lemb, bq, bk, bv, bo, Wq, Wk, Wv, Wo, A, Wt, bcat);

  // token QKV: [16384, 9216]; 64 x 36 tiles = 2304
  gemm256<<<dim3(64 * 36), dim3(512), 65536, stream>>>(A, Wt, bcat, QKV, NQKV, 36);
  // landmark QKV: split-K=6 partials, then combine (+KT/VT scatter fused)
  lm_gemm_part<<<dim3(432), dim3(256), 0, stream>>>(
      A + (size_t)MTOK * KDIM, Wt, lmp, NQKV);
  lm_gemm_fix<<<dim3(576), dim3(256), 0, stream>>>(
      lmp, bcat, QKV + (size_t)MTOK * NQKV, NQKV, KT, VT);

  // fused attention: glob (512 blocks) + lm partials (512 blocks)
  attn_fused<<<dim3(1024), dim3(256), 0, stream>>>(QKV, KT, VT, CTX, cpart, ml);
  lm_combine<<<dim3(64), dim3(256), 0, stream>>>(cpart, ml, CTX);

  // landmark PROJ: split-K=6
  lm_gemm_part<<<dim3(144), dim3(256), 0, stream>>>(
      CTX + (size_t)MTOK * DMODEL, Wt + (size_t)9216 * KDIM, lmp, DMODEL);
  lm_gemm_fix<<<dim3(192), dim3(256), 0, stream>>>(
      lmp, bcat + 9216, PROJ + (size_t)MTOK * DMODEL, DMODEL, nullptr, nullptr);

  // token out-projection: [16384, 3072]; 64 x 12 tiles = 768
  gemm256<<<dim3(64 * 12), dim3(512), 65536, stream>>>(
      CTX, Wt + (size_t)9216 * KDIM, bcat + 9216, PROJ, DMODEL, 12);

  compose<<<dim3(24576), dim3(256), 0, stream>>>(hs, PROJ, out);
}

// Round 14
// 1875.934 us; speedup vs baseline: 1.0727x; 1.0727x over previous
//
#include <hip/hip_runtime.h>
#include <stdint.h>

// ---------------- problem constants ----------------
#define S_LEN   8192
#define DMODEL  3072
#define HDIM    768
#define NLM     32
#define MTOK    16384          // B*S token rows
#define MV      16448          // + 2*32 landmark rows
#define MP      16512          // padded (A/CTX allocation rows)
#define NQKV    9216
#define KDIM    3072
#define NKT     48             // K-tiles of 64
#define MTILES  64             // M-tiles of 256 (TOKEN rows only)
#define SCALE_F 0.036084391824351615f   // 1/sqrt(768)

// ---------------- workspace layout (bytes) ----------------
#define OFF_A    ((size_t)0)
#define OFF_WT   ((size_t)101449728)
#define OFF_QKV  ((size_t)176947200)
#define OFF_CTX  ((size_t)480116736)
#define OFF_BCAT ((size_t)581566464)
#define OFF_PART ((size_t)581615616)
#define OFF_KT   (OFF_PART)
#define OFF_VT   (OFF_PART + 393216)
#define OFF_ML2  (OFF_PART + 786432)
#define OFF_LMP  (OFF_PART + 917504)   // 6 x 64 x 9216 f32 = 14.2 MB
#define OFF_CP   (OFF_A)               // lm ctx partials: 16384 x 768 f32

#if defined(__has_builtin)
#if __has_builtin(__builtin_amdgcn_global_load_lds)
#define USE_GLL 1
#endif
#endif
#ifndef USE_GLL
#define USE_GLL 0
#endif

typedef __attribute__((ext_vector_type(8))) short bf8_t;             // 8 bf16 (4 VGPR) MFMA frag
typedef __attribute__((ext_vector_type(4))) float f4_t;
typedef __attribute__((ext_vector_type(4))) short s4_t;
typedef __attribute__((ext_vector_type(4))) unsigned short us4_t;

__device__ __forceinline__ float b2f(unsigned short u) {
  unsigned x = ((unsigned)u) << 16;
  float f;
  __builtin_memcpy(&f, &x, 4);
  return f;
}
__device__ __forceinline__ unsigned short f2b(float f) {  // RNE bf16
  unsigned x;
  __builtin_memcpy(&x, &f, 4);
  x += 0x7fffu + ((x >> 16) & 1u);
  return (unsigned short)(x >> 16);
}
__device__ __forceinline__ void load12(const unsigned short* p, float* f) {
  s4_t v0 = *(const s4_t*)p;
  s4_t v1 = *(const s4_t*)(p + 4);
  s4_t v2 = *(const s4_t*)(p + 8);
#pragma unroll
  for (int e = 0; e < 4; ++e) {
    f[e]     = b2f((unsigned short)v0[e]);
    f[4 + e] = b2f((unsigned short)v1[e]);
    f[8 + e] = b2f((unsigned short)v2[e]);
  }
}
__device__ __forceinline__ void store12(unsigned short* p, const float* f) {
  us4_t a = {f2b(f[0]), f2b(f[1]), f2b(f[2]), f2b(f[3])};
  us4_t b = {f2b(f[4]), f2b(f[5]), f2b(f[6]), f2b(f[7])};
  us4_t c = {f2b(f[8]), f2b(f[9]), f2b(f[10]), f2b(f[11])};
  *(us4_t*)p = a;
  *(us4_t*)(p + 4) = b;
  *(us4_t*)(p + 8) = c;
}

// ---------------- K0: fused prep — bcat | A-matrix | weight transpose x4 ------
__global__ __launch_bounds__(256) void prep(const float* __restrict__ hs,
                                            const float* __restrict__ lemb,
                                            const float* __restrict__ bq,
                                            const float* __restrict__ bk,
                                            const float* __restrict__ bv,
                                            const float* __restrict__ bo,
                                            const float* __restrict__ W0,
                                            const float* __restrict__ W1,
                                            const float* __restrict__ W2,
                                            const float* __restrict__ W3,
                                            unsigned short* __restrict__ A,
                                            unsigned short* __restrict__ Wt,
                                            float* __restrict__ bcat) {
  __shared__ float t[32][33];
  int blk = blockIdx.x;
  int tid = threadIdx.x;
  if (blk < 48) {                                    // ---- bcat
    int n = blk * 256 + tid;                         // 0..12287
    float v = (n < 3072) ? bq[n] : (n < 6144) ? bk[n - 3072]
            : (n < 9216) ? bv[n - 6144] : bo[n - 9216];
    bcat[n] = v;
    return;
  }
  if (blk < 48 + 49536) {                            // ---- build_a
    size_t idx = (size_t)(blk - 48) * 256 + tid;
    size_t e = idx * 4;
    int row = (int)(e / DMODEL);
    int col = (int)(e - (size_t)row * DMODEL);
    f4_t v;
    if (row < MTOK) {
      v = *(const f4_t*)(hs + e);
    } else if (row < MV) {
      int r2 = row - MTOK;
      int b = r2 >> 5, j = r2 & 31;
      int sel = (j * 511) / 31;        // matches linspace(0,511,32) truncation
      int li = sel * 16;
      f4_t a = *(const f4_t*)(hs + ((size_t)(b * S_LEN + li)) * DMODEL + col);
      f4_t c = *(const f4_t*)(lemb + (size_t)j * DMODEL + col);
      v = a + c;
    } else {
      v = (f4_t){0.f, 0.f, 0.f, 0.f};
    }
    us4_t o = {f2b(v[0]), f2b(v[1]), f2b(v[2]), f2b(v[3])};
    *(us4_t*)(A + e) = o;
    return;
  }
  // ---- wtrans x4 (flattened 96x96x4)
  int i2 = blk - 49584;
  int z = i2 / 9216;
  int rem = i2 - z * 9216;
  int by = rem / 96, bx = rem - by * 96;
  const float* Wsel[4] = {W0, W1, W2, W3};
  const float* W = Wsel[z];
  unsigned short* dst = Wt + (size_t)z * 3072 * KDIM;
  int n0 = bx * 32, k0 = by * 32;
  int x = tid & 31, y = tid >> 5;                    // (32,8)
#pragma unroll
  for (int i = 0; i < 4; ++i)
    t[y + i * 8][x] = W[(size_t)(k0 + y + i * 8) * DMODEL + n0 + x];
  __syncthreads();
#pragma unroll
  for (int i = 0; i < 4; ++i)
    dst[(size_t)(n0 + y + i * 8) * DMODEL + k0 + x] = f2b(t[x][y + i * 8]);
}

// ---------------- K1b: split-K landmark GEMM partials ----------------
__global__ __launch_bounds__(256) void lm_gemm_part(const unsigned short* __restrict__ A64,
                                                    const unsigned short* __restrict__ Bt,
                                                    float* __restrict__ part,
                                                    int N) {
  int wid = blockIdx.x * 4 + (threadIdx.x >> 6);
  int lane = threadIdx.x & 63;
  int row16 = lane & 15, quad = lane >> 4;
  int strips = N >> 5;
  int ks = wid / strips;
  int n0 = (wid - ks * strips) * 32;

  f4_t acc[4][2];
#pragma unroll
  for (int mi = 0; mi < 4; ++mi) {
    acc[mi][0] = (f4_t){0.f, 0.f, 0.f, 0.f};
    acc[mi][1] = (f4_t){0.f, 0.f, 0.f, 0.f};
  }
#pragma unroll 4
  for (int kt = ks * 16; kt < ks * 16 + 16; ++kt) {
    int k = kt * 32 + quad * 8;
    bf8_t b0 = *(const bf8_t*)(Bt + (size_t)(n0 + row16) * KDIM + k);
    bf8_t b1 = *(const bf8_t*)(Bt + (size_t)(n0 + 16 + row16) * KDIM + k);
#pragma unroll
    for (int mi = 0; mi < 4; ++mi) {
      bf8_t a = *(const bf8_t*)(A64 + (size_t)(mi * 16 + row16) * KDIM + k);
      acc[mi][0] = __builtin_amdgcn_mfma_f32_16x16x32_bf16(a, b0, acc[mi][0], 0, 0, 0);
      acc[mi][1] = __builtin_amdgcn_mfma_f32_16x16x32_bf16(a, b1, acc[mi][1], 0, 0, 0);
    }
  }
#pragma unroll
  for (int mi = 0; mi < 4; ++mi)
#pragma unroll
    for (int i = 0; i < 4; ++i) {
      int r = mi * 16 + quad * 4 + i;
#pragma unroll
      for (int nl = 0; nl < 2; ++nl) {
        int col = n0 + nl * 16 + row16;
        part[((size_t)ks * 64 + r) * N + col] = acc[mi][nl][i];
      }
    }
}

// ---------------- K1c: combine split-K partials + bias -> bf16 (+ optional KT/VT) ----
__global__ __launch_bounds__(256) void lm_gemm_fix(const float* __restrict__ part,
                                                   const float* __restrict__ bias,
                                                   unsigned short* __restrict__ C64,
                                                   int N,
                                                   unsigned short* __restrict__ KT,
                                                   unsigned short* __restrict__ VT) {
  int idx = blockIdx.x * 256 + threadIdx.x;          // one f32x4 per thread
  int nq = N >> 2;
  int r = idx / nq;
  int c4 = (idx - r * nq) * 4;
  if (r >= 64) return;
  f4_t s = *(const f4_t*)(part + (size_t)r * N + c4);
#pragma unroll
  for (int ks = 1; ks < 6; ++ks)
    s += *(const f4_t*)(part + ((size_t)ks * 64 + r) * N + c4);
  f4_t bb = *(const f4_t*)(bias + c4);
  s += bb;
  us4_t o = {f2b(s[0]), f2b(s[1]), f2b(s[2]), f2b(s[3])};
  *(us4_t*)(C64 + (size_t)r * N + c4) = o;

  if (KT) {
    int b = r >> 5, j = r & 31;
    if (c4 >= 3072 && c4 < 6144) {                   // K third -> KT
      int cc = c4 - 3072;
      int h = cc / 768, c0 = cc - h * 768;           // c0 4-aligned
      int bh = b * 4 + h;
      *(us4_t*)(KT + (size_t)bh * 24576 + ((size_t)(c0 >> 3) * 32 + j) * 8 + (c0 & 7)) = o;
    } else if (c4 >= 6144) {                         // V third -> VT
      int cc = c4 - 6144;
      int h = cc / 768, d0 = cc - h * 768;
      int bh = b * 4 + h;
      unsigned short* vt = VT + (size_t)bh * 24576 + (size_t)d0 * 32 + j;
#pragma unroll
      for (int k = 0; k < 4; ++k) vt[(size_t)k * 32] = (unsigned short)o[k];
    }
  }
}

// ---------------- K2: 256x256 8-phase bf16 MFMA GEMM (token rows, M=16384) -----
// PROVEN config (R9/R12: 1914/1916us total): BK=64, 128KB LDS,
// launch_bounds(512,2), VGPR 124.  Occupancy lever CLOSED:
//   R11 (512,4): 128-VGPR cap -> acc spill (26GB scratch) -> 10x regression.
//   R13 BK=32 + (512,2): VGPR 92, no spill, but dispatcher still ran
//   1 block/CU (Occupancy 22%) and shallow prefetch cost +77us.
#if USE_GLL
#define GLL16(SRC, OFF)                                                        \
  __builtin_amdgcn_global_load_lds(                                           \
      (const __attribute__((address_space(1))) void*)(SRC),                   \
      (__attribute__((address_space(3))) void*)(lds + (OFF)), 16, 0, 0)
#else
#define GLL16(SRC, OFF)                                                        \
  (*(bf8_t*)(lds + (OFF) + (unsigned)(threadIdx.x & 63) * 16) = *(const bf8_t*)(SRC))
#endif

#define STG_A(TT, KH, DD)                                                      \
  do {                                                                         \
    const unsigned short* _s = gA0 + (size_t)(TT) * 64 + (KH) * 32;            \
    GLL16(_s, (unsigned)((DD) * 32768 + (KH) * 16384) + wl16);                 \
    GLL16(_s + (size_t)128 * KDIM,                                             \
          (unsigned)((DD) * 32768 + (KH) * 16384 + 8192) + wl16);              \
  } while (0)
#define STG_B(TT, KH, DD)                                                      \
  do {                                                                         \
    const unsigned short* _s = gB0 + (size_t)(TT) * 64 + (KH) * 32;            \
    GLL16(_s, (unsigned)(65536 + (DD) * 32768 + (KH) * 16384) + wl16);         \
    GLL16(_s + (size_t)128 * KDIM,                                             \
          (unsigned)(65536 + (DD) * 32768 + (KH) * 16384 + 8192) + wl16);      \
  } while (0)

#define LDA8(DD, KH, QM, MI)                                                   \
  (*(const bf8_t*)(lds + (DD) * 32768 + (KH) * 16384 + aBase + (QM) * 4096 +   \
                   (MI) * 1024))
#define LDB8(DD, KH, NI)                                                       \
  (*(const bf8_t*)(lds + (DD) * 32768 + (KH) * 16384 + bBase + (NI) * 1024))

#define MFMA16(Q, A0, A1, A2, A3, B0, B1, B2, B3)                              \
  do {                                                                         \
    __builtin_amdgcn_s_setprio(1);                                             \
    acc[(Q)+0][0] = __builtin_amdgcn_mfma_f32_16x16x32_bf16(A0, B0, acc[(Q)+0][0], 0, 0, 0); \
    acc[(Q)+1][0] = __builtin_amdgcn_mfma_f32_16x16x32_bf16(A1, B0, acc[(Q)+1][0], 0, 0, 0); \
    acc[(Q)+2][0] = __builtin_amdgcn_mfma_f32_16x16x32_bf16(A2, B0, acc[(Q)+2][0], 0, 0, 0); \
    acc[(Q)+3][0] = __builtin_amdgcn_mfma_f32_16x16x32_bf16(A3, B0, acc[(Q)+3][0], 0, 0, 0); \
    acc[(Q)+0][1] = __builtin_amdgcn_mfma_f32_16x16x32_bf16(A0, B1, acc[(Q)+0][1], 0, 0, 0); \
    acc[(Q)+1][1] = __builtin_amdgcn_mfma_f32_16x16x32_bf16(A1, B1, acc[(Q)+1][1], 0, 0, 0); \
    acc[(Q)+2][1] = __builtin_amdgcn_mfma_f32_16x16x32_bf16(A2, B1, acc[(Q)+2][1], 0, 0, 0); \
    acc[(Q)+3][1] = __builtin_amdgcn_mfma_f32_16x16x32_bf16(A3, B1, acc[(Q)+3][1], 0, 0, 0); \
    acc[(Q)+0][2] = __builtin_amdgcn_mfma_f32_16x16x32_bf16(A0, B2, acc[(Q)+0][2], 0, 0, 0); \
    acc[(Q)+1][2] = __builtin_amdgcn_mfma_f32_16x16x32_bf16(A1, B2, acc[(Q)+1][2], 0, 0, 0); \
    acc[(Q)+2][2] = __builtin_amdgcn_mfma_f32_16x16x32_bf16(A2, B2, acc[(Q)+2][2], 0, 0, 0); \
    acc[(Q)+3][2] = __builtin_amdgcn_mfma_f32_16x16x32_bf16(A3, B2, acc[(Q)+3][2], 0, 0, 0); \
    acc[(Q)+0][3] = __builtin_amdgcn_mfma_f32_16x16x32_bf16(A0, B3, acc[(Q)+0][3], 0, 0, 0); \
    acc[(Q)+1][3] = __builtin_amdgcn_mfma_f32_16x16x32_bf16(A1, B3, acc[(Q)+1][3], 0, 0, 0); \
    acc[(Q)+2][3] = __builtin_amdgcn_mfma_f32_16x16x32_bf16(A2, B3, acc[(Q)+2][3], 0, 0, 0); \
    acc[(Q)+3][3] = __builtin_amdgcn_mfma_f32_16x16x32_bf16(A3, B3, acc[(Q)+3][3], 0, 0, 0); \
    __builtin_amdgcn_s_setprio(0);                                             \
  } while (0)

__global__ __launch_bounds__(512, 2) void gemm256(const unsigned short* __restrict__ A,
                                                  const unsigned short* __restrict__ Bt,
                                                  const float* __restrict__ bias,
                                                  unsigned short* __restrict__ C,
                                                  int N, int Ntiles) {
  extern __shared__ char lds[];
  const int tid = threadIdx.x;
  const int lane = tid & 63;
  const int wave = tid >> 6;
  const int WM = wave >> 2;                          // 0..1 (128-row half)
  const int WN = wave & 3;                           // 0..3 (64-col strip)
  const int row16 = lane & 15, quad = lane >> 4;

  // T1: bijective XCD-aware remap (m204)
  int nwg = (int)gridDim.x;
  int orig = (int)blockIdx.x;
  int q = nwg >> 3, r = nwg & 7;
  int xcd = orig & 7, lin = orig >> 3;
  int wg = (xcd < r ? xcd * (q + 1) : r * (q + 1) + (xcd - r) * q) + lin;

  // N-group-major tile order, N_RECT=8: (g, m, nl) with nl fastest.
  int g = wg / (MTILES * 8);
  int w2 = wg - g * (MTILES * 8);
  int Ng = Ntiles - g * 8;
  int m_, nl;
  if (Ng >= 8) { m_ = w2 >> 3; nl = w2 & 7; }
  else         { m_ = w2 / Ng; nl = w2 - m_ * Ng; }
  const int tileM = m_ * 256;
  const int tileN = (g * 8 + nl) * 256;

  const int srow2 = tid >> 2;                        // 0..127
  const int scq = (tid & 3) ^ ((srow2 >> 1) & 3);    // f(row) = (row>>1)&3
  const unsigned short* gA0 = A + (size_t)(tileM + srow2) * KDIM + scq * 8;
  const unsigned short* gB0 = Bt + (size_t)(tileN + srow2) * KDIM + scq * 8;
  const unsigned wl16 = (unsigned)(tid & 448) * 16;  // wave-uniform LDS base part

  const unsigned co = (unsigned)((quad * 16) ^ (((row16 >> 1) & 3) << 4));
  const unsigned aBase = (unsigned)(WM * 8192 + row16 * 64) + co;
  const unsigned bBase = 65536u + (unsigned)(WN * 4096 + row16 * 64) + co;

  f4_t acc[8][4];
#pragma unroll
  for (int a = 0; a < 8; ++a)
#pragma unroll
    for (int b = 0; b < 4; ++b) acc[a][b] = (f4_t){0.f, 0.f, 0.f, 0.f};

  STG_B(0, 0, 0); STG_A(0, 0, 0); STG_B(0, 1, 0); STG_A(0, 1, 0);
  STG_B(1, 0, 1); STG_A(1, 0, 1); STG_B(1, 1, 1);
  asm volatile("s_waitcnt vmcnt(6)" ::: "memory");
  __builtin_amdgcn_s_barrier();

#pragma unroll 2
  for (int t = 0; t < NKT; ++t) {
    const int d = t & 1;
    {  // P0: kk=0, qm=0
      bf8_t a0 = LDA8(d, 0, 0, 0), a1 = LDA8(d, 0, 0, 1),
            a2 = LDA8(d, 0, 0, 2), a3 = LDA8(d, 0, 0, 3);
      bf8_t b0 = LDB8(d, 0, 0), b1 = LDB8(d, 0, 1),
            b2 = LDB8(d, 0, 2), b3 = LDB8(d, 0, 3);
      if (t + 1 < NKT) STG_A(t + 1, 1, d ^ 1);
      __builtin_amdgcn_s_barrier();
      asm volatile("s_waitcnt lgkmcnt(0)");
      MFMA16(0, a0, a1, a2, a3, b0, b1, b2, b3);
      __builtin_amdgcn_s_barrier();
      // P1: kk=0, qm=1
      bf8_t a4 = LDA8(d, 0, 1, 0), a5 = LDA8(d, 0, 1, 1),
            a6 = LDA8(d, 0, 1, 2), a7 = LDA8(d, 0, 1, 3);
      if (t + 2 < NKT) STG_B(t + 2, 0, d);
      __builtin_amdgcn_s_barrier();
      asm volatile("s_waitcnt lgkmcnt(0)");
      MFMA16(4, a4, a5, a6, a7, b0, b1, b2, b3);
      __builtin_amdgcn_s_barrier();
    }
    {  // P2: kk=1, qm=0
      bf8_t a0 = LDA8(d, 1, 0, 0), a1 = LDA8(d, 1, 0, 1),
            a2 = LDA8(d, 1, 0, 2), a3 = LDA8(d, 1, 0, 3);
      bf8_t b0 = LDB8(d, 1, 0), b1 = LDB8(d, 1, 1),
            b2 = LDB8(d, 1, 2), b3 = LDB8(d, 1, 3);
      if (t + 2 < NKT) STG_A(t + 2, 0, d);
      __builtin_amdgcn_s_barrier();
      asm volatile("s_waitcnt lgkmcnt(0)");
      MFMA16(0, a0, a1, a2, a3, b0, b1, b2, b3);
      __builtin_amdgcn_s_barrier();
      // P3: kk=1, qm=1 ; counted vmcnt (never 0 in steady state)
      bf8_t a4 = LDA8(d, 1, 1, 0), a5 = LDA8(d, 1, 1, 1),
            a6 = LDA8(d, 1, 1, 2), a7 = LDA8(d, 1, 1, 3);
      if (t + 2 < NKT) STG_B(t + 2, 1, d);
      __builtin_amdgcn_s_barrier();
      asm volatile("s_waitcnt lgkmcnt(0)");
      MFMA16(4, a4, a5, a6, a7, b0, b1, b2, b3);
      if (t + 2 < NKT) asm volatile("s_waitcnt vmcnt(6)" ::: "memory");
      else             asm volatile("s_waitcnt vmcnt(0)" ::: "memory");
      __builtin_amdgcn_s_barrier();
    }
  }

  float bv_[4];
#pragma unroll
  for (int ni = 0; ni < 4; ++ni) bv_[ni] = bias[tileN + WN * 64 + ni * 16 + row16];
#pragma unroll
  for (int mi = 0; mi < 8; ++mi) {
#pragma unroll
    for (int i = 0; i < 4; ++i) {
      int grow = tileM + WM * 128 + mi * 16 + quad * 4 + i;
      size_t base = (size_t)grow * N + tileN + WN * 64 + row16;
#pragma unroll
      for (int ni = 0; ni < 4; ++ni)
        C[base + ni * 16] = f2b(acc[mi][ni][i] + bv_[ni]);
    }
  }
}

// ---------------- K3: fused attention — glob_attn + lm_attn_part ----------------
__global__ __launch_bounds__(256, 2) void attn_fused(const unsigned short* __restrict__ QKV,
                                                     const unsigned short* __restrict__ KT,
                                                     const unsigned short* __restrict__ VT,
                                                     unsigned short* __restrict__ CTX,
                                                     float* __restrict__ ctxpart,
                                                     float* __restrict__ mlpart) {
  __shared__ unsigned short P_s[4][32][32];          // [wave][row][landmark]
  const int tid = threadIdx.x;
  const int lane = tid & 63;
  const int row16 = lane & 15, quad = lane >> 4;

  if (blockIdx.x < 512) {
    // ================= glob_attn =================
    const int w = tid >> 6;
    const int qt = blockIdx.x & 63;
    const int h = (blockIdx.x >> 6) & 3;
    const int b = blockIdx.x >> 8;
    const int bh = b * 4 + h;
    const int rowbase = b * S_LEN + qt * 128 + w * 32;

    const unsigned short* KTb = KT + (size_t)bh * 24576;
    const unsigned short* VTb = VT + (size_t)bh * 24576;

    f4_t sc[2][2];
#pragma unroll
    for (int mi = 0; mi < 2; ++mi)
#pragma unroll
      for (int ni = 0; ni < 2; ++ni) sc[mi][ni] = (f4_t){0.f, 0.f, 0.f, 0.f};

#pragma unroll
    for (int kt = 0; kt < 24; ++kt) {
      bf8_t kb0 = *(const bf8_t*)(KTb + (size_t)((kt * 4 + quad) * 32 + row16) * 8);
      bf8_t kb1 = *(const bf8_t*)(KTb + (size_t)((kt * 4 + quad) * 32 + 16 + row16) * 8);
      bf8_t qa0 = *(const bf8_t*)(QKV + (size_t)(rowbase + row16) * NQKV + h * HDIM +
                                  kt * 32 + quad * 8);
      bf8_t qa1 = *(const bf8_t*)(QKV + (size_t)(rowbase + 16 + row16) * NQKV + h * HDIM +
                                  kt * 32 + quad * 8);
      sc[0][0] = __builtin_amdgcn_mfma_f32_16x16x32_bf16(qa0, kb0, sc[0][0], 0, 0, 0);
      sc[0][1] = __builtin_amdgcn_mfma_f32_16x16x32_bf16(qa0, kb1, sc[0][1], 0, 0, 0);
      sc[1][0] = __builtin_amdgcn_mfma_f32_16x16x32_bf16(qa1, kb0, sc[1][0], 0, 0, 0);
      sc[1][1] = __builtin_amdgcn_mfma_f32_16x16x32_bf16(qa1, kb1, sc[1][1], 0, 0, 0);
    }

#pragma unroll
    for (int mi = 0; mi < 2; ++mi) {
#pragma unroll
      for (int i = 0; i < 4; ++i) {
        float s0 = sc[mi][0][i] * SCALE_F;
        float s1 = sc[mi][1][i] * SCALE_F;
        float mx = fmaxf(s0, s1);
#pragma unroll
        for (int off = 8; off; off >>= 1) mx = fmaxf(mx, __shfl_xor(mx, off));
        float p0 = __expf(s0 - mx), p1 = __expf(s1 - mx);
        float sum = p0 + p1;
#pragma unroll
        for (int off = 8; off; off >>= 1) sum += __shfl_xor(sum, off);
        float inv = 1.f / sum;
        int rr = mi * 16 + quad * 4 + i;
        P_s[w][rr][row16] = f2b(p0 * inv);
        P_s[w][rr][16 + row16] = f2b(p1 * inv);
      }
    }
    __syncthreads();

    bf8_t pa0 = *(const bf8_t*)&P_s[w][row16][quad * 8];
    bf8_t pa1 = *(const bf8_t*)&P_s[w][16 + row16][quad * 8];
    unsigned short* ctxb = CTX + (size_t)rowbase * DMODEL + h * HDIM;

#pragma unroll
    for (int dch = 0; dch < 12; ++dch) {
      bf8_t vb[4];
#pragma unroll
      for (int ni = 0; ni < 4; ++ni)
        vb[ni] = *(const bf8_t*)(VTb + (size_t)(dch * 64 + ni * 16 + row16) * 32 + quad * 8);
#pragma unroll
      for (int mi = 0; mi < 2; ++mi) {
        bf8_t pa = mi ? pa1 : pa0;
#pragma unroll
        for (int ni = 0; ni < 4; ++ni) {
          f4_t c = __builtin_amdgcn_mfma_f32_16x16x32_bf16(
              pa, vb[ni], (f4_t){0.f, 0.f, 0.f, 0.f}, 0, 0, 0);
#pragma unroll
          for (int i = 0; i < 4; ++i)
            ctxb[(size_t)(mi * 16 + quad * 4 + i) * DMODEL + dch * 64 + ni * 16 + row16] =
                f2b(c[i]);
        }
      }
    }
    return;
  }

  // ================= lm_attn_part (JG=8, 64 k-chunks of 128) =================
  int wid = (blockIdx.x - 512) * 4 + (tid >> 6);     // 0..2047
  int jg = wid & 3, kc = (wid >> 2) & 63, h = (wid >> 8) & 3, b = wid >> 10;

  float qreg[8][12];
#pragma unroll
  for (int jj = 0; jj < 8; ++jj)
    load12(QKV + (size_t)(MTOK + b * NLM + jg * 8 + jj) * NQKV + h * HDIM + lane * 12,
           qreg[jj]);

  float m[8], l[8], ctx[8][12];
#pragma unroll
  for (int jj = 0; jj < 8; ++jj) {
    m[jj] = -1e30f;
    l[jj] = 0.f;
#pragma unroll
    for (int e = 0; e < 12; ++e) ctx[jj][e] = 0.f;
  }

  for (int k = kc * 128; k < kc * 128 + 128; ++k) {
    size_t row = (size_t)(b * S_LEN + k);
    float kv[12], vv[12];
    load12(QKV + row * NQKV + DMODEL + h * HDIM + lane * 12, kv);
    float s[8];
#pragma unroll
    for (int jj = 0; jj < 8; ++jj) {
      float p = 0.f;
#pragma unroll
      for (int e = 0; e < 12; ++e) p += qreg[jj][e] * kv[e];
      s[jj] = p;
    }
#pragma unroll
    for (int jj = 0; jj < 8; ++jj) {
#pragma unroll
      for (int off = 32; off; off >>= 1) s[jj] += __shfl_xor(s[jj], off);
      s[jj] *= SCALE_F;
    }
    load12(QKV + row * NQKV + 2 * DMODEL + h * HDIM + lane * 12, vv);
#pragma unroll
    for (int jj = 0; jj < 8; ++jj) {
      if (s[jj] <= m[jj]) {                          // wave-uniform branch
        float pp = __expf(s[jj] - m[jj]);
        l[jj] += pp;
#pragma unroll
        for (int e = 0; e < 12; ++e) ctx[jj][e] += pp * vv[e];
      } else {
        float al = __expf(m[jj] - s[jj]);
        m[jj] = s[jj];
        l[jj] = l[jj] * al + 1.f;
#pragma unroll
        for (int e = 0; e < 12; ++e) ctx[jj][e] = ctx[jj][e] * al + vv[e];
      }
    }
  }

#pragma unroll
  for (int jj = 0; jj < 8; ++jj) {
    int p = (((b * 4 + h) * 32) + (jg * 8 + jj)) * 64 + kc;
    float* cp = ctxpart + (size_t)p * HDIM + lane * 12;
#pragma unroll
    for (int e = 0; e < 12; ++e) cp[e] = ctx[jj][e];
    if (lane == 0) {
      mlpart[p * 2] = m[jj];
      mlpart[p * 2 + 1] = l[jj];
    }
  }
}

// ---------------- K4b: merge 64 landmark partials, wave per (b,h,j) ----------------
__global__ __launch_bounds__(256) void lm_combine(const float* __restrict__ ctxpart,
                                                  const float* __restrict__ mlpart,
                                                  unsigned short* __restrict__ CTX) {
  int wid = blockIdx.x * 4 + (threadIdx.x >> 6);     // 0..255
  int lane = threadIdx.x & 63;
  int j = wid & 31, h = (wid >> 5) & 3, b = wid >> 7;
  int base = wid * 64;
  float mk = mlpart[(base + lane) * 2];
  float lk = mlpart[(base + lane) * 2 + 1];
  float mm = mk;
#pragma unroll
  for (int off = 32; off; off >>= 1) mm = fmaxf(mm, __shfl_xor(mm, off));
  float al = __expf(mk - mm);
  float ls = al * lk;
#pragma unroll
  for (int off = 32; off; off >>= 1) ls += __shfl_xor(ls, off);

  float ctx[12];
#pragma unroll
  for (int e = 0; e < 12; ++e) ctx[e] = 0.f;
  for (int kc = 0; kc < 64; ++kc) {
    float a = __shfl(al, kc);
    const float* cp = ctxpart + (size_t)(base + kc) * HDIM + lane * 12;
#pragma unroll
    for (int e = 0; e < 12; ++e) ctx[e] += a * cp[e];
  }
  float inv = 1.f / ls;
#pragma unroll
  for (int e = 0; e < 12; ++e) ctx[e] *= inv;
  store12(CTX + (size_t)(MTOK + b * NLM + j) * DMODEL + h * HDIM + lane * 12, ctx);
}

// ---------------- K6: out = (landmark? lm_proj : hs) + global_proj, 8 elems/thread ----
__global__ __launch_bounds__(256) void compose(const float* __restrict__ hs,
                                               const unsigned short* __restrict__ PROJ,
                                               float* __restrict__ out) {
  size_t idx = (size_t)blockIdx.x * 256 + threadIdx.x;
  size_t e = idx * 8;
  int row = (int)(e / DMODEL);
  int col = (int)(e - (size_t)row * DMODEL);
  int b = row >> 13, s = row & (S_LEN - 1);

  us4_t g4a = *(const us4_t*)(PROJ + (size_t)row * DMODEL + col);
  us4_t g4b = *(const us4_t*)(PROJ + (size_t)row * DMODEL + col + 4);
  int j = -1;
  if ((s & 15) == 0) {
    int sel = s >> 4;
    int jc = (sel * 31 + 510) / 511;                 // ceil(sel*31/511): unique candidate
    if (jc < 32 && (jc * 511) / 31 == sel) j = jc;
  }
  f4_t ba, bb;
  if (j >= 0) {
    const unsigned short* lp = PROJ + (size_t)(MTOK + b * NLM + j) * DMODEL + col;
    us4_t l4a = *(const us4_t*)lp;
    us4_t l4b = *(const us4_t*)(lp + 4);
    ba = (f4_t){b2f(l4a[0]), b2f(l4a[1]), b2f(l4a[2]), b2f(l4a[3])};
    bb = (f4_t){b2f(l4b[0]), b2f(l4b[1]), b2f(l4b[2]), b2f(l4b[3])};
  } else {
    ba = *(const f4_t*)(hs + e);
    bb = *(const f4_t*)(hs + e + 4);
  }
  f4_t oa = {ba[0] + b2f(g4a[0]), ba[1] + b2f(g4a[1]),
             ba[2] + b2f(g4a[2]), ba[3] + b2f(g4a[3])};
  f4_t ob = {bb[0] + b2f(g4b[0]), bb[1] + b2f(g4b[1]),
             bb[2] + b2f(g4b[2]), bb[3] + b2f(g4b[3])};
  *(f4_t*)(out + e) = oa;
  *(f4_t*)(out + e + 4) = ob;
}

// ---------------- launch ----------------
extern "C" void kernel_launch(void* const* d_in, const int* in_sizes, int n_in,
                              void* d_out, int out_size, void* d_ws, size_t ws_size,
                              hipStream_t stream) {
  const float* hs   = (const float*)d_in[0];
  const float* lemb = (const float*)d_in[1];
  const float* Wq   = (const float*)d_in[2];
  const float* bq   = (const float*)d_in[3];
  const float* Wk   = (const float*)d_in[4];
  const float* bk   = (const float*)d_in[5];
  const float* Wv   = (const float*)d_in[6];
  const float* bv   = (const float*)d_in[7];
  const float* Wo   = (const float*)d_in[8];
  const float* bo   = (const float*)d_in[9];
  float* out = (float*)d_out;
  char* ws = (char*)d_ws;

  unsigned short* A    = (unsigned short*)(ws + OFF_A);
  unsigned short* Wt   = (unsigned short*)(ws + OFF_WT);
  unsigned short* QKV  = (unsigned short*)(ws + OFF_QKV);
  unsigned short* CTX  = (unsigned short*)(ws + OFF_CTX);
  float*          bcat = (float*)(ws + OFF_BCAT);
  unsigned short* KT   = (unsigned short*)(ws + OFF_KT);
  unsigned short* VT   = (unsigned short*)(ws + OFF_VT);
  float*          ml   = (float*)(ws + OFF_ML2);
  float*          lmp  = (float*)(ws + OFF_LMP);
  float*          cpart= (float*)(ws + OFF_CP);          // A region (dead window)
  unsigned short* PROJ = (unsigned short*)(ws + OFF_A);  // after lm_combine

  static bool attr_set = false;
  if (!attr_set) {
    (void)hipFuncSetAttribute(reinterpret_cast<const void*>(gemm256),
                              hipFuncAttributeMaxDynamicSharedMemorySize, 131072);
    attr_set = true;
  }

  // fused prep: bcat(48) + build_a(49536) + wtrans(36864)
  prep<<<dim3(48 + 49536 + 36864), dim3(256), 0, stream>>>(
      hs, lemb, bq, bk, bv, bo, Wq, Wk, Wv, Wo, A, Wt, bcat);

  // token QKV: [16384, 9216]; 64 x 36 tiles = 2304 = 9 rounds exactly
  gemm256<<<dim3(64 * 36), dim3(512), 131072, stream>>>(A, Wt, bcat, QKV, NQKV, 36);
  // landmark QKV: split-K=6 partials, then combine (+KT/VT scatter fused)
  lm_gemm_part<<<dim3(432), dim3(256), 0, stream>>>(
      A + (size_t)MTOK * KDIM, Wt, lmp, NQKV);
  lm_gemm_fix<<<dim3(576), dim3(256), 0, stream>>>(
      lmp, bcat, QKV + (size_t)MTOK * NQKV, NQKV, KT, VT);

  // fused attention: glob (512 blocks) + lm partials (512 blocks)
  attn_fused<<<dim3(1024), dim3(256), 0, stream>>>(QKV, KT, VT, CTX, cpart, ml);
  lm_combine<<<dim3(64), dim3(256), 0, stream>>>(cpart, ml, CTX);

  // landmark PROJ: split-K=6
  lm_gemm_part<<<dim3(144), dim3(256), 0, stream>>>(
      CTX + (size_t)MTOK * DMODEL, Wt + (size_t)9216 * KDIM, lmp, DMODEL);
  lm_gemm_fix<<<dim3(192), dim3(256), 0, stream>>>(
      lmp, bcat + 9216, PROJ + (size_t)MTOK * DMODEL, DMODEL, nullptr, nullptr);

  // token out-projection: [16384, 3072]; 64 x 12 tiles = 768 = 3 rounds exactly
  gemm256<<<dim3(64 * 12), dim3(512), 131072, stream>>>(
      CTX, Wt + (size_t)9216 * KDIM, bcat + 9216, PROJ, DMODEL, 12);

  compose<<<dim3(24576), dim3(256), 0, stream>>>(hs, PROJ, out);
}